// Round 8
// baseline (952.586 us; speedup 1.0000x reference)
//
#include <hip/hip_runtime.h>
#include <math.h>

#define DIM 128
#define HID 256
#define MT 64           // rows per block-tile (2 halves of 32)
#define NT 1024         // 16 waves: crew A (stage-1) = waves 0-7, crew B (stage-2) = waves 8-15
#define H_STRIDE 136    // bf16 elems
#define G_STRIDE 264    // bf16 elems, k-permuted packed layout
#define S_STRIDE 132    // f32 elems (stBuf / gsBuf)

typedef __attribute__((ext_vector_type(8))) short bf16x8;
typedef __attribute__((ext_vector_type(4))) float f32x4;
typedef __attribute__((ext_vector_type(4))) unsigned int u32x4;

#define MFMA(a, b, c) __builtin_amdgcn_mfma_f32_16x16x32_bf16((a), (b), (c), 0, 0, 0)

__device__ __forceinline__ unsigned int pack2(float lo, float hi) {
    unsigned int a = __float_as_uint(lo) + 0x8000u;
    unsigned int b = __float_as_uint(hi) + 0x8000u;
    return __builtin_amdgcn_perm(b, a, 0x07060302u);  // [b.hi16 | a.hi16]
}
__device__ __forceinline__ unsigned short rb16(float f) {
    return (unsigned short)((__float_as_uint(f) + 0x8000u) >> 16);
}
__device__ __forceinline__ float frcp(float x) { return __builtin_amdgcn_rcpf(x); }
__device__ __forceinline__ float ex2(float x)  { return __builtin_amdgcn_exp2f(x); }
__device__ __forceinline__ float gelu_f(float t) {
    const float u = t * fmaf(t * t, -0.1029436f, -2.3022082f);
    return t * frcp(1.f + ex2(u));
}
__device__ __forceinline__ float sigm(float x) { return frcp(1.f + ex2(-1.442695f * x)); }
__device__ __forceinline__ f32x4 splat4(float v) { f32x4 r = {v, v, v, v}; return r; }

// ---- setup: w2g = w2 @ wg_r (256x128 @ 128x128) -> ws fp32; row 256 = bg + b2 @ wg_r ----
__global__ void w2g_setup(const float* __restrict__ w2, const float* __restrict__ wg,
                          const float* __restrict__ b2, const float* __restrict__ bg,
                          float* __restrict__ w2g)
{
    __shared__ float wr[DIM][DIM + 1];
    const int t = threadIdx.x;  // 256
    for (int i = t; i < DIM * DIM; i += 256)
        wr[i >> 7][i & 127] = wg[DIM * DIM + i];  // wg_r = wg[128:,:]
    __syncthreads();
    const int row = blockIdx.x * 32 + (t >> 3);  // 8 blocks x 32 rows
    const int c0  = (t & 7) * 16;
    float acc[16];
#pragma unroll
    for (int j = 0; j < 16; ++j) acc[j] = 0.f;
    for (int k = 0; k < DIM; ++k) {
        const float a = w2[row * DIM + k];
#pragma unroll
        for (int j = 0; j < 16; ++j) acc[j] = fmaf(a, wr[k][c0 + j], acc[j]);
    }
#pragma unroll
    for (int j = 0; j < 16; ++j) w2g[row * DIM + c0 + j] = acc[j];
    if (blockIdx.x == 0 && t < DIM) {
        float s = bg[t];
        for (int k = 0; k < DIM; ++k) s = fmaf(b2[k], wr[k][t], s);
        w2g[256 * DIM + t] = s;
    }
}

// Wave-specialized (round-6 structure, verified at 833us / Occ 45.8%): crews A/B
// hold stage-1/stage-2 weights; uniform barriers; shared wf[16] pool. Round-6
// counters showed MFMA (25.7%) and VALU (47%) serializing. This round (resubmit
// of round 7 after an infra flake): T5 s_setprio around MFMA clusters — the
// mechanism requires role-split waves per phase, which this structure has
// (each SIMD carries 2 crew-A + 2 crew-B waves in different roles per phase).
__global__ __launch_bounds__(NT) void trw_kernel(
    const float* __restrict__ x,
    const float* __restrict__ ln_w, const float* __restrict__ ln_b,
    const float* __restrict__ w1, const float* __restrict__ b1,
    const float* __restrict__ w2, const float* __restrict__ b2,
    const float* __restrict__ wg,
    const float* __restrict__ w2g,
    const int* __restrict__ passes_p,
    float* __restrict__ out, int nrows)
{
    __shared__ __align__(16) unsigned short hBuf[MT * H_STRIDE];  // 17408 B
    __shared__ __align__(16) unsigned short gBuf[MT * G_STRIDE];  // 33792 B
    __shared__ __align__(16) float gsBuf[MT * S_STRIDE];          // 33792 B
    __shared__ __align__(16) float stBuf[MT * S_STRIDE];          // 33792 B
    __shared__ __align__(16) float muB[MT];
    __shared__ __align__(16) float sgB[MT];
    unsigned int* gBuf32 = (unsigned int*)gBuf;

    const int tid = threadIdx.x;
    const bool crewA = (tid < 512);
    const int ct = tid & 511;           // crew-local thread id
    const int wv = (tid >> 6) & 7;      // crew-local wave id
    const int l = tid & 63, q = l >> 4, c16 = l & 15;
    const int colG = 16 * wv + c16;
    const int np = passes_p[0];
    const int nTiles = nrows / MT;

    // ---- shared weight-fragment pool + biases ----
    bf16x8 wf[16];
    {
        bf16x8 z;
#pragma unroll
        for (int j = 0; j < 8; ++j) z[j] = 0;
#pragma unroll
        for (int i = 0; i < 16; ++i) wf[i] = z;
    }
    float bias0 = 0.f, bias1 = 0.f, bias2 = 0.f;

    if (crewA) {
        // crew A: wf[kk]=w1'A, wf[4+kk]=w1'B, wf[8+kk]=wg_s ; bias0/1=b1', bias2=cs1
        const int colA = 32 * wv + c16, colB = colA + 16;
#pragma unroll
        for (int kk = 0; kk < 4; ++kk) {
#pragma unroll
            for (int j = 0; j < 8; ++j) {
                const int k = kk * 32 + q * 8 + j;
                const float lwk = ln_w[k];
                wf[kk][j]     = (short)rb16(lwk * w1[k * HID + colA]);
                wf[4 + kk][j] = (short)rb16(lwk * w1[k * HID + colB]);
                wf[8 + kk][j] = (short)rb16(wg[k * DIM + colG]);
            }
        }
        bias0 = b1[colA]; bias1 = b1[colB]; bias2 = 0.f;
        for (int k = 0; k < DIM; ++k) {
            const float lbk = ln_b[k];
            bias0 = fmaf(lbk, w1[k * HID + colA], bias0);
            bias1 = fmaf(lbk, w1[k * HID + colB], bias1);
            bias2 += wg[k * DIM + colG];
        }
    } else {
        // crew B: wf[kk]=w2 (k-permuted), wf[8+kk]=w2g ; bias0=b2, bias1=bg'
#pragma unroll
        for (int kk = 0; kk < 8; ++kk) {
#pragma unroll
            for (int j = 0; j < 8; ++j) {
                const int pk = kk * 32 + q * 8 + j;
                const int p5 = pk & 31;
                const int L  = (pk & ~31) + ((p5 & 1) << 4) + (p5 >> 1);
                wf[kk][j]     = (short)rb16(w2[L * DIM + colG]);
                wf[8 + kk][j] = (short)rb16(w2g[L * DIM + colG]);
            }
        }
        bias0 = b2[colG]; bias1 = w2g[256 * DIM + colG];
    }

#define LOADX(H)                                                                        \
    {                                                                                   \
        const int row = (H) * 32 + (ct >> 4);                                           \
        const int hc  = (ct & 15) << 3;                                                 \
        const float* xr = x + (size_t)(tile * MT + row) * DIM + hc;                     \
        *(f32x4*)&stBuf[row * S_STRIDE + hc]     = *(const f32x4*)(xr);                 \
        *(f32x4*)&stBuf[row * S_STRIDE + hc + 4] = *(const f32x4*)(xr + 4);             \
    }

#define FIN(H)                                                                          \
    {                                                                                   \
        const int row = (H) * 32 + (ct >> 4);                                           \
        const int hc  = (ct & 15) << 3;                                                 \
        float* orow = out + (size_t)(tile * MT + row) * DIM + hc;                       \
        *(f32x4*)(orow)     = *(f32x4*)&stBuf[row * S_STRIDE + hc];                     \
        *(f32x4*)(orow + 4) = *(f32x4*)&stBuf[row * S_STRIDE + hc + 4];                 \
    }

    // HUB(H): LN over stBuf rows of half H -> packed h' in hBuf + muB/sgB
#define HUB(H)                                                                          \
    {                                                                                   \
        const int row = (H) * 32 + (ct >> 4);                                           \
        const int hc  = (ct & 15) << 3;                                                 \
        f32x4 a0 = *(f32x4*)&stBuf[row * S_STRIDE + hc];                                \
        f32x4 a1 = *(f32x4*)&stBuf[row * S_STRIDE + hc + 4];                            \
        float s1 = 0.f, s2 = 0.f;                                                       \
        _Pragma("unroll")                                                               \
        for (int j = 0; j < 4; ++j) {                                                   \
            s1 += a0[j] + a1[j];                                                        \
            s2 = fmaf(a0[j], a0[j], fmaf(a1[j], a1[j], s2));                            \
        }                                                                               \
        _Pragma("unroll")                                                               \
        for (int m = 8; m >= 1; m >>= 1) { s1 += __shfl_xor(s1, m); s2 += __shfl_xor(s2, m); } \
        const float mu = s1 * (1.f / DIM);                                              \
        const float ve = fmaf(-mu, mu, s2 * (1.f / DIM)) + 1e-5f;                       \
        const float rs = rsqrtf(ve);                                                    \
        const float mrs = mu * rs;                                                      \
        u32x4 hv = {pack2(fmaf(a0[0], rs, -mrs), fmaf(a0[1], rs, -mrs)),                \
                    pack2(fmaf(a0[2], rs, -mrs), fmaf(a0[3], rs, -mrs)),                \
                    pack2(fmaf(a1[0], rs, -mrs), fmaf(a1[1], rs, -mrs)),                \
                    pack2(fmaf(a1[2], rs, -mrs), fmaf(a1[3], rs, -mrs))};               \
        *(u32x4*)&hBuf[row * H_STRIDE + hc] = hv;                                       \
        if ((ct & 15) == 0) { muB[row] = mu; sgB[row] = ve * rs; }                      \
    }

    // M1(H): crew A — [t0 t1 | gs] = h' @ [w1' | wg_s]; gelu->gBuf, gs->gsBuf
    // setprio(1) around the MFMA cluster (T5): lets the CU scheduler push this
    // wave's MFMA under the other crew's VALU phase instead of fair-interleaving.
#define M1(H)                                                                           \
    {                                                                                   \
        f32x4 acc0[2], acc1[2], accg[2];                                                \
        _Pragma("unroll")                                                               \
        for (int rt = 0; rt < 2; ++rt) {                                                \
            acc0[rt] = splat4(bias0); acc1[rt] = splat4(bias1); accg[rt] = splat4(0.f); \
        }                                                                               \
        __builtin_amdgcn_s_setprio(1);                                                  \
        _Pragma("unroll")                                                               \
        for (int rt = 0; rt < 2; ++rt)                                                  \
            _Pragma("unroll")                                                           \
            for (int kk = 0; kk < 4; ++kk) {                                            \
                bf16x8 a = *(bf16x8*)&hBuf[((H) * 32 + rt * 16 + c16) * H_STRIDE + kk * 32 + q * 8]; \
                acc0[rt] = MFMA(a, wf[kk], acc0[rt]);                                   \
                acc1[rt] = MFMA(a, wf[4 + kk], acc1[rt]);                               \
                accg[rt] = MFMA(a, wf[8 + kk], accg[rt]);                               \
            }                                                                           \
        __builtin_amdgcn_s_setprio(0);                                                  \
        _Pragma("unroll")                                                               \
        for (int rt = 0; rt < 2; ++rt) {                                                \
            f32x4 muv = *(f32x4*)&muB[(H) * 32 + rt * 16 + q * 4];                      \
            f32x4 sgv = *(f32x4*)&sgB[(H) * 32 + rt * 16 + q * 4];                      \
            _Pragma("unroll")                                                           \
            for (int r = 0; r < 4; ++r) {                                               \
                const int row = (H) * 32 + rt * 16 + q * 4 + r;                         \
                gBuf32[row * (G_STRIDE / 2) + colG] =                                   \
                    pack2(gelu_f(acc0[rt][r]), gelu_f(acc1[rt][r]));                    \
                gsBuf[row * S_STRIDE + colG] = fmaf(sgv[r], accg[rt][r], muv[r] * bias2); \
            }                                                                           \
        }                                                                               \
    }

    // M2(H): crew B — [refined | gr] = g @ [w2 | w2g]; gate; delta accumulated into stBuf
#define M2(H)                                                                           \
    {                                                                                   \
        f32x4 acc2[2], accr[2];                                                         \
        _Pragma("unroll")                                                               \
        for (int rt = 0; rt < 2; ++rt) { acc2[rt] = splat4(bias0); accr[rt] = splat4(bias1); } \
        __builtin_amdgcn_s_setprio(1);                                                  \
        _Pragma("unroll")                                                               \
        for (int rt = 0; rt < 2; ++rt)                                                  \
            _Pragma("unroll")                                                           \
            for (int kk = 0; kk < 8; ++kk) {                                            \
                bf16x8 a = *(bf16x8*)&gBuf[((H) * 32 + rt * 16 + c16) * G_STRIDE + kk * 32 + q * 8]; \
                acc2[rt] = MFMA(a, wf[kk], acc2[rt]);                                   \
                accr[rt] = MFMA(a, wf[8 + kk], accr[rt]);                               \
            }                                                                           \
        __builtin_amdgcn_s_setprio(0);                                                  \
        _Pragma("unroll")                                                               \
        for (int rt = 0; rt < 2; ++rt)                                                  \
            _Pragma("unroll")                                                           \
            for (int r = 0; r < 4; ++r) {                                               \
                const int row = (H) * 32 + rt * 16 + q * 4 + r;                         \
                const int idx = row * S_STRIDE + colG;                                  \
                const float gate = sigm(gsBuf[idx] + accr[rt][r]);                      \
                stBuf[idx] += gate * acc2[rt][r];                                       \
            }                                                                           \
    }

    for (int tile = blockIdx.x; tile < nTiles; tile += gridDim.x) {
        if (crewA) { LOADX(0) } else { LOADX(1) }
        __syncthreads();                          // S1: stBuf ready
        if (!crewA) { HUB(1) }
        __syncthreads();                          // S2: hBuf(H1) ready
        for (int p = 0; p < np; ++p) {
            if (crewA) { M1(1) } else { HUB(0) }  // Phi1
            __syncthreads();                      // S3
            if (crewA) { M1(0) } else { M2(1) }   // Phi2
            __syncthreads();                      // S4
            if (crewA) { if (p < np - 1) HUB(1) } else { M2(0) }  // Phi3
            __syncthreads();                      // S5
        }
        if (crewA) { FIN(0) } else { FIN(1) }
        __syncthreads();                          // S6: protect stBuf before next LOADX
    }
#undef LOADX
#undef FIN
#undef HUB
#undef M1
#undef M2
}

extern "C" void kernel_launch(void* const* d_in, const int* in_sizes, int n_in,
                              void* d_out, int out_size, void* d_ws, size_t ws_size,
                              hipStream_t stream) {
    const float* x    = (const float*)d_in[0];
    const float* ln_w = (const float*)d_in[1];
    const float* ln_b = (const float*)d_in[2];
    const float* w1   = (const float*)d_in[3];
    const float* b1   = (const float*)d_in[4];
    const float* w2   = (const float*)d_in[5];
    const float* b2   = (const float*)d_in[6];
    const float* wg   = (const float*)d_in[7];
    const float* bg   = (const float*)d_in[8];
    const int* passes = (const int*)d_in[9];
    float* out = (float*)d_out;
    float* w2g = (float*)d_ws;  // 257*128 fp32 = 131584 B

    const int nrows = in_sizes[0] / DIM;
    hipLaunchKernelGGL(w2g_setup, dim3(8), dim3(256), 0, stream, w2, wg, b2, bg, w2g);
    hipLaunchKernelGGL(trw_kernel, dim3(1024), dim3(NT), 0, stream,
                       x, ln_w, ln_b, w1, b1, w2, b2, wg, w2g, passes, out, nrows);
}